// Round 17
// baseline (1930.315 us; speedup 1.0000x reference)
//
#include <hip/hip_runtime.h>

typedef float f32x4 __attribute__((ext_vector_type(4)));
typedef short s16x8 __attribute__((ext_vector_type(8)));
typedef short s16x4 __attribute__((ext_vector_type(4)));

#define NB 16
#define NPT 4096
#define DPT 254
#define NS 1024
#define KNN 16
#define NPAIR (NB*NS*KNN)   // 262144
#define NROWS (NB*NPT)      // 65536

__device__ __forceinline__ unsigned short f2bf(float f) {
  unsigned u = __float_as_uint(f);
  u += 0x7FFFu + ((u >> 16) & 1u);   // RNE
  return (unsigned short)(u >> 16);
}
__device__ __forceinline__ float bf2f(unsigned short h) {
  return __uint_as_float(((unsigned)h) << 16);
}
// monotone float->uint order map (handles negatives)
__device__ __forceinline__ unsigned ordf(float f) {
  unsigned u = __float_as_uint(f);
  return u ^ (unsigned)(((int)u >> 31) | 0x80000000);
}
// contraction-proof f32 RN ops
__device__ __forceinline__ float vmulf(float a, float b) {
  float r; asm("v_mul_f32 %0, %1, %2" : "=v"(r) : "v"(a), "v"(b)); return r;
}
__device__ __forceinline__ float vaddf(float a, float b) {
  float r; asm("v_add_f32 %0, %1, %2" : "=v"(r) : "v"(a), "v"(b)); return r;
}
__device__ __forceinline__ float vsubf(float a, float b) {
  float r; asm("v_sub_f32 %0, %1, %2" : "=v"(r) : "v"(a), "v"(b)); return r;
}
// explicit single fma
__device__ __forceinline__ float vfmaf(float a, float b, float c) {
  float r; asm("v_fma_f32 %0, %1, %2, %3" : "=v"(r) : "v"(a), "v"(b), "v"(c)); return r;
}

// ---------------- K0: convert W1/W2 to bf16 staged layout [chunk][col][kk] ----------------
__global__ __launch_bounds__(256) void k_conv(const float* __restrict__ W1, const float* __restrict__ W2,
                                              unsigned short* __restrict__ W1s, unsigned short* __restrict__ W2s) {
  int i = blockIdx.x * 256 + threadIdx.x;
  if (i < 8 * 512 * 32) {
    int kk = i & 31, col = (i >> 5) & 511, c = i >> 14;
    W1s[i] = f2bf(W1[(c * 32 + kk) * 512 + col]);
  }
  if (i < 16 * 512 * 32) {
    int kk = i & 31, col = (i >> 5) & 511, c = i >> 14;
    W2s[i] = f2bf(W2[(c * 32 + kk) * 512 + col]);
  }
}

// ---------------- K1: FPS f32 direct SOP (out0-verified across all variants) ----------------
__global__ __launch_bounds__(256) void k_fps(const float* __restrict__ xy, int* __restrict__ fpsi) {
  const int b = blockIdx.x;
  const int t = threadIdx.x;
  __shared__ float sx[NPT], sy[NPT];
  __shared__ unsigned long long wkey[2][4];
  __shared__ int sfar[2];
  for (int i = t; i < NPT; i += 256) {
    float2 v = ((const float2*)xy)[b * NPT + i];
    sx[i] = v.x; sy[i] = v.y;
  }
  __syncthreads();
  float px[16], py[16], dist[16];
  #pragma unroll
  for (int j = 0; j < 16; ++j) {
    int i = t + 256 * j;
    px[j] = sx[i]; py[j] = sy[i]; dist[j] = 1e10f;
  }
  int far = 0;
  if (t == 0) fpsi[b * NS] = 0;
  for (int step = 1; step < NS; ++step) {
    const float cx = sx[far], cy = sy[far];
    float bd = -1.0f; int bi = 0;
    #pragma unroll
    for (int j = 0; j < 16; ++j) {
      float dx = vsubf(px[j], cx), dy = vsubf(py[j], cy);
      float d = vaddf(vmulf(dx, dx), vmulf(dy, dy));
      float nd = fminf(dist[j], d);
      dist[j] = nd;
      if (nd > bd) { bd = nd; bi = t + 256 * j; }
    }
    unsigned long long key = ((unsigned long long)ordf(bd) << 32) | (unsigned)(0xFFFFFFFFu ^ (unsigned)bi);
    #pragma unroll
    for (int off = 32; off; off >>= 1) {
      unsigned long long o = __shfl_xor(key, off);
      key = (o > key) ? o : key;
    }
    if ((t & 63) == 0) wkey[step & 1][t >> 6] = key;
    __syncthreads();
    if (t == 0) {
      unsigned long long k0 = wkey[step & 1][0], k1 = wkey[step & 1][1];
      unsigned long long k2 = wkey[step & 1][2], k3 = wkey[step & 1][3];
      unsigned long long m = k0 > k1 ? k0 : k1;
      unsigned long long n = k2 > k3 ? k2 : k3;
      m = m > n ? m : n;
      int fi = (int)(0xFFFFFFFFu ^ (unsigned)m);
      sfar[step & 1] = fi;
      fpsi[b * NS + step] = fi;
    }
    __syncthreads();
    far = sfar[step & 1];
  }
}

// ---------------- K2: 16-NN; dot = fma(qy,by, RN(qx*bx)) — XLA/np ascending-c FMA reduce ----------------
__global__ __launch_bounds__(256) void k_knn(const float* __restrict__ xy, const int* __restrict__ fpsi,
                                             int* __restrict__ knni, float* __restrict__ xyn,
                                             float* __restrict__ out_newxy) {
  const int q = blockIdx.x;           // b*NS + s
  const int b = q >> 10;
  const int t = threadIdx.x;
  __shared__ unsigned long long wmin[2][4];
  const int qi = fpsi[q];
  float2 qv = ((const float2*)xy)[b * NPT + qi];
  const float qx = qv.x, qy = qv.y;
  if (t == 0) { out_newxy[q * 2 + 0] = qx; out_newxy[q * 2 + 1] = qy; }
  const float sa = vaddf(vmulf(qx, qx), vmulf(qy, qy));
  float px[16], py[16];
  unsigned long long ku[16], cmin = ~0ull;
  #pragma unroll
  for (int j = 0; j < 16; ++j) {
    const int i = t + 256 * j;
    float2 v = ((const float2*)xy)[b * NPT + i];
    px[j] = v.x; py[j] = v.y;
    const float sb = vaddf(vmulf(v.x, v.x), vmulf(v.y, v.y));
    const float dot = vfmaf(qy, v.y, vmulf(qx, v.x));   // acc=RN(qx*bx); dot=fma(qy,by,acc)
    const float d = vsubf(vaddf(sa, sb), vmulf(2.0f, dot));
    ku[j] = ((unsigned long long)ordf(d) << 32) | (unsigned)i;   // tie: lowest index first
    cmin = ku[j] < cmin ? ku[j] : cmin;
  }
  for (int r = 0; r < KNN; ++r) {
    unsigned long long key = cmin;
    #pragma unroll
    for (int off = 32; off; off >>= 1) {
      unsigned long long o = __shfl_xor(key, off);
      key = o < key ? o : key;
    }
    if ((t & 63) == 0) wmin[r & 1][t >> 6] = key;
    __syncthreads();
    unsigned long long m0 = wmin[r & 1][0], m1 = wmin[r & 1][1];
    unsigned long long m2 = wmin[r & 1][2], m3 = wmin[r & 1][3];
    unsigned long long m = m0 < m1 ? m0 : m1;
    unsigned long long n = m2 < m3 ? m2 : m3;
    m = m < n ? m : n;
    if (m == cmin) {  // unique owner (idx embedded in key)
      const unsigned widx = (unsigned)m;
      const int jj0 = (int)(widx >> 8);
      cmin = ~0ull;
      #pragma unroll
      for (int j = 0; j < 16; ++j) {
        if (j == jj0) {
          ku[j] = ~0ull;
          knni[q * KNN + r] = (int)widx;
          xyn[(q * KNN + r) * 2 + 0] = vsubf(px[j], qx);
          xyn[(q * KNN + r) * 2 + 1] = vsubf(py[j], qy);
        }
        cmin = ku[j] < cmin ? ku[j] : cmin;
      }
    }
  }
}

// ---------------- K3: P1 = pad2(points) @ W1  (bf16 MFMA), tile 64x512 ----------------
__global__ __launch_bounds__(256) void k_p1(const float* __restrict__ points,
                                            const unsigned short* __restrict__ W1s,
                                            unsigned short* __restrict__ P1) {
  const int rt = blockIdx.x;
  const int t = threadIdx.x, l = t & 63, w = t >> 6;
  __shared__ unsigned short sA[64 * 40];
  __shared__ unsigned short sB[512 * 40];
  f32x4 acc[4][8];
  #pragma unroll
  for (int mi = 0; mi < 4; ++mi)
    #pragma unroll
    for (int ni = 0; ni < 8; ++ni) acc[mi][ni] = (f32x4){0.f, 0.f, 0.f, 0.f};
  for (int c = 0; c < 8; ++c) {
    __syncthreads();
    {
      const int r = t >> 2, kk = (t & 3) * 8;
      const int m = rt * 64 + r;
      s16x8 av;
      #pragma unroll
      for (int j = 0; j < 8; ++j) {
        const int cc = c * 32 + kk + j;
        const float f = (cc >= 2) ? points[(size_t)m * DPT + (cc - 2)] : 0.0f;
        av[j] = (short)f2bf(f);
      }
      *(s16x8*)(&sA[r * 40 + kk]) = av;
    }
    {
      const unsigned short* src = &W1s[c * 16384];
      #pragma unroll
      for (int qd = 0; qd < 8; ++qd) {
        const int e = t * 64 + qd * 8;
        const int col = e >> 5, kk = e & 31;
        *(s16x8*)(&sB[col * 40 + kk]) = *(const s16x8*)(&src[e]);
      }
    }
    __syncthreads();
    s16x8 a[4];
    #pragma unroll
    for (int mi = 0; mi < 4; ++mi)
      a[mi] = *(const s16x8*)(&sA[(mi * 16 + (l & 15)) * 40 + (l >> 4) * 8]);
    #pragma unroll
    for (int ni = 0; ni < 8; ++ni) {
      const s16x8 bv = *(const s16x8*)(&sB[(w * 128 + ni * 16 + (l & 15)) * 40 + (l >> 4) * 8]);
      #pragma unroll
      for (int mi = 0; mi < 4; ++mi)
        acc[mi][ni] = __builtin_amdgcn_mfma_f32_16x16x32_bf16(a[mi], bv, acc[mi][ni], 0, 0, 0);
    }
  }
  #pragma unroll
  for (int mi = 0; mi < 4; ++mi)
    #pragma unroll
    for (int ni = 0; ni < 8; ++ni)
      #pragma unroll
      for (int r = 0; r < 4; ++r) {
        const int row = rt * 64 + mi * 16 + (l >> 4) * 4 + r;
        const int col = w * 128 + ni * 16 + (l & 15);
        P1[(size_t)row * 512 + col] = f2bf(acc[mi][ni][r]);
      }
}

// ---------------- K4: layer-1 pre-activation stats ----------------
__global__ __launch_bounds__(256) void k_stats1(const unsigned short* __restrict__ P1,
                                                const int* __restrict__ knni, const float* __restrict__ xyn,
                                                const float* __restrict__ W1, const float* __restrict__ b1,
                                                float* __restrict__ part1) {
  const int blk = blockIdx.x;
  const int t = threadIdx.x;
  __shared__ int sgidx[256];
  __shared__ float sxn[256][2];
  const int p = blk * 256 + t;
  const int b = p >> 14;
  sgidx[t] = b * NPT + knni[p];
  sxn[t][0] = xyn[p * 2 + 0]; sxn[t][1] = xyn[p * 2 + 1];
  __syncthreads();
  const int ch0 = 2 * t;
  const float w00 = W1[ch0], w01 = W1[ch0 + 1];
  const float w10 = W1[512 + ch0], w11 = W1[512 + ch0 + 1];
  const float bb0 = b1[ch0], bb1 = b1[ch0 + 1];
  float s0 = 0, s1 = 0, q0 = 0, q1 = 0;
  for (int i = 0; i < 256; ++i) {
    const int row = sgidx[i];
    const float xn = sxn[i][0], yn = sxn[i][1];
    unsigned v = *(const unsigned*)(&P1[(size_t)row * 512 + ch0]);
    float z0 = bf2f((unsigned short)v) + xn * w00 + yn * w10 + bb0;
    float z1 = bf2f((unsigned short)(v >> 16)) + xn * w01 + yn * w11 + bb1;
    s0 += z0; q0 += z0 * z0; s1 += z1; q1 += z1 * z1;
  }
  float4 o; o.x = s0; o.y = q0; o.z = s1; o.w = q1;
  *(float4*)(&part1[(size_t)(blk * 512 + ch0) * 2]) = o;
}

// ---------------- column reduce ----------------
__global__ __launch_bounds__(256) void k_colreduce(const float* __restrict__ part, int rows_per_blk,
                                                   float* __restrict__ out) {
  const int cs = blockIdx.x & 3, rs = blockIdx.x >> 2;
  const int col = cs * 256 + threadIdx.x;
  float s = 0;
  const int r0 = rs * rows_per_blk;
  for (int r = 0; r < rows_per_blk; ++r) s += part[(size_t)(r0 + r) * 1024 + col];
  out[rs * 1024 + col] = s;
}

// ---------------- K5: finalize BN1 ----------------
__global__ __launch_bounds__(256) void k_fin1(const float* __restrict__ tmp1, const float* __restrict__ W1,
                                              const float* __restrict__ b1, const float* __restrict__ g1,
                                              const float* __restrict__ bt1, float4* __restrict__ coef1) {
  const int ch = blockIdx.x * 256 + threadIdx.x;
  float s = 0, q = 0;
  #pragma unroll
  for (int r = 0; r < 4; ++r) { s += tmp1[r * 1024 + 2 * ch]; q += tmp1[r * 1024 + 2 * ch + 1]; }
  const float inv = 1.0f / 262144.0f;
  const float m = s * inv;
  const float var = q * inv - m * m;
  const float A = rsqrtf(var + 1e-5f) * g1[ch];
  const float Bv = bt1[ch] - m * A;
  float4 cf;
  cf.x = A; cf.y = W1[ch] * A; cf.z = W1[512 + ch] * A; cf.w = b1[ch] * A + Bv;
  coef1[ch] = cf;
}

// ---------------- K6: fused h1 -> GEMM2 -> z2 stats + max/min over K ----------------
__global__ __launch_bounds__(256) void k_main(const unsigned short* __restrict__ P1,
                                              const int* __restrict__ knni, const float* __restrict__ xyn,
                                              const float4* __restrict__ coef1,
                                              const unsigned short* __restrict__ W2s,
                                              const float* __restrict__ b2,
                                              float* __restrict__ part2,
                                              unsigned short* __restrict__ zmaxh, unsigned short* __restrict__ zminh) {
  const int g = blockIdx.x;
  const int t = threadIdx.x, l = t & 63, w = t >> 6;
  __shared__ unsigned short sH[64 * 40];
  __shared__ unsigned short sW[512 * 40];
  __shared__ int sgidx[64];
  __shared__ float sxn[64][2];
  if (t < 64) {
    const int p = g * 64 + t;
    const int b = p >> 14;
    sgidx[t] = b * NPT + knni[p];
    sxn[t][0] = xyn[p * 2 + 0]; sxn[t][1] = xyn[p * 2 + 1];
  }
  f32x4 acc[4][8];
  #pragma unroll
  for (int mi = 0; mi < 4; ++mi)
    #pragma unroll
    for (int ni = 0; ni < 8; ++ni) acc[mi][ni] = (f32x4){0.f, 0.f, 0.f, 0.f};
  const int skk = t & 31;
  const int sr0 = (t >> 5) * 8;
  for (int c = 0; c < 16; ++c) {
    __syncthreads();
    {
      const int ch = c * 32 + skk;
      const float4 cf = coef1[ch];
      #pragma unroll
      for (int qq = 0; qq < 8; ++qq) {
        const int r = sr0 + qq;
        const int row = sgidx[r];
        const float pv = bf2f(P1[(size_t)row * 512 + ch]);
        const float h = fmaxf(0.0f, pv * cf.x + sxn[r][0] * cf.y + sxn[r][1] * cf.z + cf.w);
        sH[r * 40 + skk] = f2bf(h);
      }
    }
    {
      const unsigned short* src = &W2s[c * 16384];
      #pragma unroll
      for (int qd = 0; qd < 8; ++qd) {
        const int e = t * 64 + qd * 8;
        const int col = e >> 5, kk = e & 31;
        *(s16x8*)(&sW[col * 40 + kk]) = *(const s16x8*)(&src[e]);
      }
    }
    __syncthreads();
    s16x8 a[4];
    #pragma unroll
    for (int mi = 0; mi < 4; ++mi)
      a[mi] = *(const s16x8*)(&sH[(mi * 16 + (l & 15)) * 40 + (l >> 4) * 8]);
    #pragma unroll
    for (int ni = 0; ni < 8; ++ni) {
      const s16x8 bv = *(const s16x8*)(&sW[(w * 128 + ni * 16 + (l & 15)) * 40 + (l >> 4) * 8]);
      #pragma unroll
      for (int mi = 0; mi < 4; ++mi)
        acc[mi][ni] = __builtin_amdgcn_mfma_f32_16x16x32_bf16(a[mi], bv, acc[mi][ni], 0, 0, 0);
    }
  }
  const int cl = l & 15, lg = l >> 4;
  #pragma unroll
  for (int ni = 0; ni < 8; ++ni) {
    const int col = w * 128 + ni * 16 + cl;
    const float b2v = b2[col];
    float colsum = 0, colssq = 0;
    #pragma unroll
    for (int mi = 0; mi < 4; ++mi) {
      f32x4 v = acc[mi][ni];
      #pragma unroll
      for (int r = 0; r < 4; ++r) v[r] += b2v;
      float mx = fmaxf(fmaxf(v[0], v[1]), fmaxf(v[2], v[3]));
      float mn = fminf(fminf(v[0], v[1]), fminf(v[2], v[3]));
      float sm = v[0] + v[1] + v[2] + v[3];
      float sq = v[0] * v[0] + v[1] * v[1] + v[2] * v[2] + v[3] * v[3];
      mx = fmaxf(mx, __shfl_xor(mx, 16)); mx = fmaxf(mx, __shfl_xor(mx, 32));
      mn = fminf(mn, __shfl_xor(mn, 16)); mn = fminf(mn, __shfl_xor(mn, 32));
      sm = sm + __shfl_xor(sm, 16); sm = sm + __shfl_xor(sm, 32);
      sq = sq + __shfl_xor(sq, 16); sq = sq + __shfl_xor(sq, 32);
      if (lg == 0) {
        const int srow = g * 4 + mi;
        zmaxh[(size_t)srow * 512 + col] = f2bf(mx);
        zminh[(size_t)srow * 512 + col] = f2bf(mn);
      }
      colsum += sm; colssq += sq;
    }
    if (lg == 0) {
      float2 o; o.x = colsum; o.y = colssq;
      *(float2*)(&part2[(size_t)(g * 512 + col) * 2]) = o;
    }
  }
}

// ---------------- K7: finalize BN2 ----------------
__global__ __launch_bounds__(256) void k_fin2(const float* __restrict__ tmp2, const float* __restrict__ g2,
                                              const float* __restrict__ bt2,
                                              float* __restrict__ A2, float* __restrict__ B2) {
  const int ch = blockIdx.x * 256 + threadIdx.x;
  float s = 0, q = 0;
  #pragma unroll
  for (int r = 0; r < 16; ++r) { s += tmp2[r * 1024 + 2 * ch]; q += tmp2[r * 1024 + 2 * ch + 1]; }
  const float inv = 1.0f / 262144.0f;
  const float m = s * inv;
  const float var = q * inv - m * m;
  const float A = rsqrtf(var + 1e-5f) * g2[ch];
  A2[ch] = A;
  B2[ch] = bt2[ch] - m * A;
}

// ---------------- K8: final BN2+ReLU ----------------
__global__ __launch_bounds__(256) void k_out(const unsigned short* __restrict__ zmaxh,
                                             const unsigned short* __restrict__ zminh,
                                             const float* __restrict__ A2, const float* __restrict__ B2,
                                             float* __restrict__ out) {
  int v = blockIdx.x * 256 + threadIdx.x;
  for (; v < 2097152; v += gridDim.x * 256) {
    const int f = v * 4;
    const int col = f & 511;
    const float4 a = *(const float4*)(&A2[col]);
    const float4 bb = *(const float4*)(&B2[col]);
    s16x4 mxh = *(const s16x4*)(&zmaxh[f]);
    s16x4 mnh = *(const s16x4*)(&zminh[f]);
    float4 o;
    o.x = fmaxf(0.f, a.x * (a.x > 0.f ? bf2f((unsigned short)mxh[0]) : bf2f((unsigned short)mnh[0])) + bb.x);
    o.y = fmaxf(0.f, a.y * (a.y > 0.f ? bf2f((unsigned short)mxh[1]) : bf2f((unsigned short)mnh[1])) + bb.y);
    o.z = fmaxf(0.f, a.z * (a.z > 0.f ? bf2f((unsigned short)mxh[2]) : bf2f((unsigned short)mnh[2])) + bb.z);
    o.w = fmaxf(0.f, a.w * (a.w > 0.f ? bf2f((unsigned short)mxh[3]) : bf2f((unsigned short)mnh[3])) + bb.w);
    *(float4*)(&out[32768 + f]) = o;
  }
}

__global__ void k_sent_ws(float* out) { if (threadIdx.x == 0) out[0] = 54321.0f; }

extern "C" void kernel_launch(void* const* d_in, const int* in_sizes, int n_in,
                              void* d_out, int out_size, void* d_ws, size_t ws_size,
                              hipStream_t stream) {
  const float* xy   = (const float*)d_in[0];
  const float* pts  = (const float*)d_in[1];
  const float* W1   = (const float*)d_in[2];
  const float* b1   = (const float*)d_in[3];
  const float* g1   = (const float*)d_in[4];
  const float* bt1  = (const float*)d_in[5];
  const float* W2   = (const float*)d_in[6];
  const float* b2   = (const float*)d_in[7];
  const float* g2   = (const float*)d_in[8];
  const float* bt2  = (const float*)d_in[9];
  float* out = (float*)d_out;
  (void)in_sizes; (void)n_in; (void)out_size;

  char* base = (char*)d_ws;
  size_t off = 0;
  auto take = [&](size_t bytes) -> char* {
    char* r = base + off;
    off = (off + bytes + 255) & ~(size_t)255;
    return r;
  };
  int*   fpsi  = (int*)take((size_t)NB * NS * 4);
  int*   knni  = (int*)take((size_t)NPAIR * 4);
  float* xyn   = (float*)take((size_t)NPAIR * 2 * 4);
  unsigned short* W1s = (unsigned short*)take((size_t)8 * 512 * 32 * 2);
  unsigned short* W2s = (unsigned short*)take((size_t)16 * 512 * 32 * 2);
  unsigned short* P1  = (unsigned short*)take((size_t)NROWS * 512 * 2);
  float* part1 = (float*)take((size_t)1024 * 1024 * 4);
  float* tmp1  = (float*)take((size_t)4 * 1024 * 4);
  float4* coef1 = (float4*)take((size_t)512 * 16);
  float* part2 = (float*)take((size_t)4096 * 1024 * 4);
  float* tmp2  = (float*)take((size_t)16 * 1024 * 4);
  float* A2    = (float*)take((size_t)512 * 4);
  float* B2    = (float*)take((size_t)512 * 4);
  unsigned short* zmaxh = (unsigned short*)take((size_t)16384 * 512 * 2);
  unsigned short* zminh = (unsigned short*)take((size_t)16384 * 512 * 2);

  if (off > ws_size) {
    k_sent_ws<<<1, 64, 0, stream>>>(out);
    return;
  }

  k_conv<<<1024, 256, 0, stream>>>(W1, W2, W1s, W2s);
  k_fps<<<NB, 256, 0, stream>>>(xy, fpsi);
  k_knn<<<NB * NS, 256, 0, stream>>>(xy, fpsi, knni, xyn, out);
  k_p1<<<1024, 256, 0, stream>>>(pts, W1s, P1);
  k_stats1<<<1024, 256, 0, stream>>>(P1, knni, xyn, W1, b1, part1);
  k_colreduce<<<16, 256, 0, stream>>>(part1, 256, tmp1);
  k_fin1<<<2, 256, 0, stream>>>(tmp1, W1, b1, g1, bt1, coef1);
  k_main<<<4096, 256, 0, stream>>>(P1, knni, xyn, coef1, W2s, b2, part2, zmaxh, zminh);
  k_colreduce<<<64, 256, 0, stream>>>(part2, 256, tmp2);
  k_fin2<<<2, 256, 0, stream>>>(tmp2, g2, bt2, A2, B2);
  k_out<<<2048, 256, 0, stream>>>(zmaxh, zminh, A2, B2, out);
}

// Round 18
// 1872.638 us; speedup vs baseline: 1.0308x; 1.0308x over previous
//
#include <hip/hip_runtime.h>

typedef float f32x4 __attribute__((ext_vector_type(4)));
typedef short s16x8 __attribute__((ext_vector_type(8)));
typedef short s16x4 __attribute__((ext_vector_type(4)));

#define NB 16
#define NPT 4096
#define DPT 254
#define NS 1024
#define KNN 16
#define NPAIR (NB*NS*KNN)   // 262144
#define NROWS (NB*NPT)      // 65536

__device__ __forceinline__ unsigned short f2bf(float f) {
  unsigned u = __float_as_uint(f);
  u += 0x7FFFu + ((u >> 16) & 1u);   // RNE
  return (unsigned short)(u >> 16);
}
__device__ __forceinline__ float bf2f(unsigned short h) {
  return __uint_as_float(((unsigned)h) << 16);
}
// monotone float->uint order map (handles negatives)
__device__ __forceinline__ unsigned ordf(float f) {
  unsigned u = __float_as_uint(f);
  return u ^ (unsigned)(((int)u >> 31) | 0x80000000);
}
// contraction-proof f32 RN ops
__device__ __forceinline__ float vmulf(float a, float b) {
  float r; asm("v_mul_f32 %0, %1, %2" : "=v"(r) : "v"(a), "v"(b)); return r;
}
__device__ __forceinline__ float vaddf(float a, float b) {
  float r; asm("v_add_f32 %0, %1, %2" : "=v"(r) : "v"(a), "v"(b)); return r;
}
__device__ __forceinline__ float vsubf(float a, float b) {
  float r; asm("v_sub_f32 %0, %1, %2" : "=v"(r) : "v"(a), "v"(b)); return r;
}
// explicit single fma
__device__ __forceinline__ float vfmaf(float a, float b, float c) {
  float r; asm("v_fma_f32 %0, %1, %2, %3" : "=v"(r) : "v"(a), "v"(b), "v"(c)); return r;
}

// ---------------- K0: convert W1/W2 to bf16 staged layout [chunk][col][kk] ----------------
__global__ __launch_bounds__(256) void k_conv(const float* __restrict__ W1, const float* __restrict__ W2,
                                              unsigned short* __restrict__ W1s, unsigned short* __restrict__ W2s) {
  int i = blockIdx.x * 256 + threadIdx.x;
  if (i < 8 * 512 * 32) {
    int kk = i & 31, col = (i >> 5) & 511, c = i >> 14;
    W1s[i] = f2bf(W1[(c * 32 + kk) * 512 + col]);
  }
  if (i < 16 * 512 * 32) {
    int kk = i & 31, col = (i >> 5) & 511, c = i >> 14;
    W2s[i] = f2bf(W2[(c * 32 + kk) * 512 + col]);
  }
}

// ---------------- K1: FPS f32 direct SOP — ONE barrier/step, no serial section ----------------
// Arithmetic and argmax tie semantics byte-identical to the verified version; only the
// reduction plumbing changed (double-buffered leader keys + all-threads final max).
__global__ __launch_bounds__(256) void k_fps(const float* __restrict__ xy, int* __restrict__ fpsi) {
  const int b = blockIdx.x;
  const int t = threadIdx.x;
  __shared__ float sx[NPT], sy[NPT];
  __shared__ unsigned long long wkey[2][4];
  for (int i = t; i < NPT; i += 256) {
    float2 v = ((const float2*)xy)[b * NPT + i];
    sx[i] = v.x; sy[i] = v.y;
  }
  __syncthreads();
  float px[16], py[16], dist[16];
  #pragma unroll
  for (int j = 0; j < 16; ++j) {
    int i = t + 256 * j;
    px[j] = sx[i]; py[j] = sy[i]; dist[j] = 1e10f;
  }
  if (t == 0) fpsi[b * NS] = 0;
  float cx = sx[0], cy = sy[0];
  for (int step = 1; step < NS; ++step) {
    float bd = -1.0f; int bi = 0;
    #pragma unroll
    for (int j = 0; j < 16; ++j) {
      float dx = vsubf(px[j], cx), dy = vsubf(py[j], cy);
      float d = vaddf(vmulf(dx, dx), vmulf(dy, dy));
      float nd = fminf(dist[j], d);
      dist[j] = nd;
      if (nd > bd) { bd = nd; bi = t + 256 * j; }
    }
    unsigned long long key = ((unsigned long long)ordf(bd) << 32) | (unsigned)(0xFFFFFFFFu ^ (unsigned)bi);
    #pragma unroll
    for (int off = 32; off; off >>= 1) {
      unsigned long long o = __shfl_xor(key, off);
      key = (o > key) ? o : key;
    }
    if ((t & 63) == 0) wkey[step & 1][t >> 6] = key;
    __syncthreads();
    unsigned long long k0 = wkey[step & 1][0], k1 = wkey[step & 1][1];
    unsigned long long k2 = wkey[step & 1][2], k3 = wkey[step & 1][3];
    unsigned long long m = k0 > k1 ? k0 : k1;
    unsigned long long n = k2 > k3 ? k2 : k3;
    m = m > n ? m : n;
    const int fi = (int)(0xFFFFFFFFu ^ (unsigned)m);
    if (t == 0) fpsi[b * NS + step] = fi;
    cx = sx[fi]; cy = sy[fi];
  }
}

// ---------------- K2: 16-NN; dot = fma(qy,by, RN(qx*bx)) — verified golden semantics ----------------
__global__ __launch_bounds__(256) void k_knn(const float* __restrict__ xy, const int* __restrict__ fpsi,
                                             int* __restrict__ knni, float* __restrict__ xyn,
                                             float* __restrict__ out_newxy) {
  const int q = blockIdx.x;           // b*NS + s
  const int b = q >> 10;
  const int t = threadIdx.x;
  __shared__ unsigned long long wmin[2][4];
  const int qi = fpsi[q];
  float2 qv = ((const float2*)xy)[b * NPT + qi];
  const float qx = qv.x, qy = qv.y;
  if (t == 0) { out_newxy[q * 2 + 0] = qx; out_newxy[q * 2 + 1] = qy; }
  const float sa = vaddf(vmulf(qx, qx), vmulf(qy, qy));
  float px[16], py[16];
  unsigned long long ku[16], cmin = ~0ull;
  #pragma unroll
  for (int j = 0; j < 16; ++j) {
    const int i = t + 256 * j;
    float2 v = ((const float2*)xy)[b * NPT + i];
    px[j] = v.x; py[j] = v.y;
    const float sb = vaddf(vmulf(v.x, v.x), vmulf(v.y, v.y));
    const float dot = vfmaf(qy, v.y, vmulf(qx, v.x));   // acc=RN(qx*bx); dot=fma(qy,by,acc)
    const float d = vsubf(vaddf(sa, sb), vmulf(2.0f, dot));
    ku[j] = ((unsigned long long)ordf(d) << 32) | (unsigned)i;   // tie: lowest index first
    cmin = ku[j] < cmin ? ku[j] : cmin;
  }
  for (int r = 0; r < KNN; ++r) {
    unsigned long long key = cmin;
    #pragma unroll
    for (int off = 32; off; off >>= 1) {
      unsigned long long o = __shfl_xor(key, off);
      key = o < key ? o : key;
    }
    if ((t & 63) == 0) wmin[r & 1][t >> 6] = key;
    __syncthreads();
    unsigned long long m0 = wmin[r & 1][0], m1 = wmin[r & 1][1];
    unsigned long long m2 = wmin[r & 1][2], m3 = wmin[r & 1][3];
    unsigned long long m = m0 < m1 ? m0 : m1;
    unsigned long long n = m2 < m3 ? m2 : m3;
    m = m < n ? m : n;
    if (m == cmin) {  // unique owner (idx embedded in key)
      const unsigned widx = (unsigned)m;
      const int jj0 = (int)(widx >> 8);
      cmin = ~0ull;
      #pragma unroll
      for (int j = 0; j < 16; ++j) {
        if (j == jj0) {
          ku[j] = ~0ull;
          knni[q * KNN + r] = (int)widx;
          xyn[(q * KNN + r) * 2 + 0] = vsubf(px[j], qx);
          xyn[(q * KNN + r) * 2 + 1] = vsubf(py[j], qy);
        }
        cmin = ku[j] < cmin ? ku[j] : cmin;
      }
    }
  }
}

// ---------------- K3: P1 = pad2(points) @ W1  (bf16 MFMA), tile 64x512 ----------------
__global__ __launch_bounds__(256) void k_p1(const float* __restrict__ points,
                                            const unsigned short* __restrict__ W1s,
                                            unsigned short* __restrict__ P1) {
  const int rt = blockIdx.x;
  const int t = threadIdx.x, l = t & 63, w = t >> 6;
  __shared__ unsigned short sA[64 * 40];
  __shared__ unsigned short sB[512 * 40];
  f32x4 acc[4][8];
  #pragma unroll
  for (int mi = 0; mi < 4; ++mi)
    #pragma unroll
    for (int ni = 0; ni < 8; ++ni) acc[mi][ni] = (f32x4){0.f, 0.f, 0.f, 0.f};
  for (int c = 0; c < 8; ++c) {
    __syncthreads();
    {
      const int r = t >> 2, kk = (t & 3) * 8;
      const int m = rt * 64 + r;
      s16x8 av;
      #pragma unroll
      for (int j = 0; j < 8; ++j) {
        const int cc = c * 32 + kk + j;
        const float f = (cc >= 2) ? points[(size_t)m * DPT + (cc - 2)] : 0.0f;
        av[j] = (short)f2bf(f);
      }
      *(s16x8*)(&sA[r * 40 + kk]) = av;
    }
    {
      const unsigned short* src = &W1s[c * 16384];
      #pragma unroll
      for (int qd = 0; qd < 8; ++qd) {
        const int e = t * 64 + qd * 8;
        const int col = e >> 5, kk = e & 31;
        *(s16x8*)(&sB[col * 40 + kk]) = *(const s16x8*)(&src[e]);
      }
    }
    __syncthreads();
    s16x8 a[4];
    #pragma unroll
    for (int mi = 0; mi < 4; ++mi)
      a[mi] = *(const s16x8*)(&sA[(mi * 16 + (l & 15)) * 40 + (l >> 4) * 8]);
    #pragma unroll
    for (int ni = 0; ni < 8; ++ni) {
      const s16x8 bv = *(const s16x8*)(&sB[(w * 128 + ni * 16 + (l & 15)) * 40 + (l >> 4) * 8]);
      #pragma unroll
      for (int mi = 0; mi < 4; ++mi)
        acc[mi][ni] = __builtin_amdgcn_mfma_f32_16x16x32_bf16(a[mi], bv, acc[mi][ni], 0, 0, 0);
    }
  }
  #pragma unroll
  for (int mi = 0; mi < 4; ++mi)
    #pragma unroll
    for (int ni = 0; ni < 8; ++ni)
      #pragma unroll
      for (int r = 0; r < 4; ++r) {
        const int row = rt * 64 + mi * 16 + (l >> 4) * 4 + r;
        const int col = w * 128 + ni * 16 + (l & 15);
        P1[(size_t)row * 512 + col] = f2bf(acc[mi][ni][r]);
      }
}

// ---------------- K4: layer-1 pre-activation stats ----------------
__global__ __launch_bounds__(256) void k_stats1(const unsigned short* __restrict__ P1,
                                                const int* __restrict__ knni, const float* __restrict__ xyn,
                                                const float* __restrict__ W1, const float* __restrict__ b1,
                                                float* __restrict__ part1) {
  const int blk = blockIdx.x;
  const int t = threadIdx.x;
  __shared__ int sgidx[256];
  __shared__ float sxn[256][2];
  const int p = blk * 256 + t;
  const int b = p >> 14;
  sgidx[t] = b * NPT + knni[p];
  sxn[t][0] = xyn[p * 2 + 0]; sxn[t][1] = xyn[p * 2 + 1];
  __syncthreads();
  const int ch0 = 2 * t;
  const float w00 = W1[ch0], w01 = W1[ch0 + 1];
  const float w10 = W1[512 + ch0], w11 = W1[512 + ch0 + 1];
  const float bb0 = b1[ch0], bb1 = b1[ch0 + 1];
  float s0 = 0, s1 = 0, q0 = 0, q1 = 0;
  for (int i = 0; i < 256; ++i) {
    const int row = sgidx[i];
    const float xn = sxn[i][0], yn = sxn[i][1];
    unsigned v = *(const unsigned*)(&P1[(size_t)row * 512 + ch0]);
    float z0 = bf2f((unsigned short)v) + xn * w00 + yn * w10 + bb0;
    float z1 = bf2f((unsigned short)(v >> 16)) + xn * w01 + yn * w11 + bb1;
    s0 += z0; q0 += z0 * z0; s1 += z1; q1 += z1 * z1;
  }
  float4 o; o.x = s0; o.y = q0; o.z = s1; o.w = q1;
  *(float4*)(&part1[(size_t)(blk * 512 + ch0) * 2]) = o;
}

// ---------------- column reduce ----------------
__global__ __launch_bounds__(256) void k_colreduce(const float* __restrict__ part, int rows_per_blk,
                                                   float* __restrict__ out) {
  const int cs = blockIdx.x & 3, rs = blockIdx.x >> 2;
  const int col = cs * 256 + threadIdx.x;
  float s = 0;
  const int r0 = rs * rows_per_blk;
  for (int r = 0; r < rows_per_blk; ++r) s += part[(size_t)(r0 + r) * 1024 + col];
  out[rs * 1024 + col] = s;
}

// ---------------- K5: finalize BN1 ----------------
__global__ __launch_bounds__(256) void k_fin1(const float* __restrict__ tmp1, const float* __restrict__ W1,
                                              const float* __restrict__ b1, const float* __restrict__ g1,
                                              const float* __restrict__ bt1, float4* __restrict__ coef1) {
  const int ch = blockIdx.x * 256 + threadIdx.x;
  float s = 0, q = 0;
  #pragma unroll
  for (int r = 0; r < 4; ++r) { s += tmp1[r * 1024 + 2 * ch]; q += tmp1[r * 1024 + 2 * ch + 1]; }
  const float inv = 1.0f / 262144.0f;
  const float m = s * inv;
  const float var = q * inv - m * m;
  const float A = rsqrtf(var + 1e-5f) * g1[ch];
  const float Bv = bt1[ch] - m * A;
  float4 cf;
  cf.x = A; cf.y = W1[ch] * A; cf.z = W1[512 + ch] * A; cf.w = b1[ch] * A + Bv;
  coef1[ch] = cf;
}

// ---------------- K6: fused h1 -> GEMM2 -> z2 stats + max/min over K ----------------
__global__ __launch_bounds__(256) void k_main(const unsigned short* __restrict__ P1,
                                              const int* __restrict__ knni, const float* __restrict__ xyn,
                                              const float4* __restrict__ coef1,
                                              const unsigned short* __restrict__ W2s,
                                              const float* __restrict__ b2,
                                              float* __restrict__ part2,
                                              unsigned short* __restrict__ zmaxh, unsigned short* __restrict__ zminh) {
  const int g = blockIdx.x;
  const int t = threadIdx.x, l = t & 63, w = t >> 6;
  __shared__ unsigned short sH[64 * 40];
  __shared__ unsigned short sW[512 * 40];
  __shared__ int sgidx[64];
  __shared__ float sxn[64][2];
  if (t < 64) {
    const int p = g * 64 + t;
    const int b = p >> 14;
    sgidx[t] = b * NPT + knni[p];
    sxn[t][0] = xyn[p * 2 + 0]; sxn[t][1] = xyn[p * 2 + 1];
  }
  f32x4 acc[4][8];
  #pragma unroll
  for (int mi = 0; mi < 4; ++mi)
    #pragma unroll
    for (int ni = 0; ni < 8; ++ni) acc[mi][ni] = (f32x4){0.f, 0.f, 0.f, 0.f};
  const int skk = t & 31;
  const int sr0 = (t >> 5) * 8;
  for (int c = 0; c < 16; ++c) {
    __syncthreads();
    {
      const int ch = c * 32 + skk;
      const float4 cf = coef1[ch];
      #pragma unroll
      for (int qq = 0; qq < 8; ++qq) {
        const int r = sr0 + qq;
        const int row = sgidx[r];
        const float pv = bf2f(P1[(size_t)row * 512 + ch]);
        const float h = fmaxf(0.0f, pv * cf.x + sxn[r][0] * cf.y + sxn[r][1] * cf.z + cf.w);
        sH[r * 40 + skk] = f2bf(h);
      }
    }
    {
      const unsigned short* src = &W2s[c * 16384];
      #pragma unroll
      for (int qd = 0; qd < 8; ++qd) {
        const int e = t * 64 + qd * 8;
        const int col = e >> 5, kk = e & 31;
        *(s16x8*)(&sW[col * 40 + kk]) = *(const s16x8*)(&src[e]);
      }
    }
    __syncthreads();
    s16x8 a[4];
    #pragma unroll
    for (int mi = 0; mi < 4; ++mi)
      a[mi] = *(const s16x8*)(&sH[(mi * 16 + (l & 15)) * 40 + (l >> 4) * 8]);
    #pragma unroll
    for (int ni = 0; ni < 8; ++ni) {
      const s16x8 bv = *(const s16x8*)(&sW[(w * 128 + ni * 16 + (l & 15)) * 40 + (l >> 4) * 8]);
      #pragma unroll
      for (int mi = 0; mi < 4; ++mi)
        acc[mi][ni] = __builtin_amdgcn_mfma_f32_16x16x32_bf16(a[mi], bv, acc[mi][ni], 0, 0, 0);
    }
  }
  const int cl = l & 15, lg = l >> 4;
  #pragma unroll
  for (int ni = 0; ni < 8; ++ni) {
    const int col = w * 128 + ni * 16 + cl;
    const float b2v = b2[col];
    float colsum = 0, colssq = 0;
    #pragma unroll
    for (int mi = 0; mi < 4; ++mi) {
      f32x4 v = acc[mi][ni];
      #pragma unroll
      for (int r = 0; r < 4; ++r) v[r] += b2v;
      float mx = fmaxf(fmaxf(v[0], v[1]), fmaxf(v[2], v[3]));
      float mn = fminf(fminf(v[0], v[1]), fminf(v[2], v[3]));
      float sm = v[0] + v[1] + v[2] + v[3];
      float sq = v[0] * v[0] + v[1] * v[1] + v[2] * v[2] + v[3] * v[3];
      mx = fmaxf(mx, __shfl_xor(mx, 16)); mx = fmaxf(mx, __shfl_xor(mx, 32));
      mn = fminf(mn, __shfl_xor(mn, 16)); mn = fminf(mn, __shfl_xor(mn, 32));
      sm = sm + __shfl_xor(sm, 16); sm = sm + __shfl_xor(sm, 32);
      sq = sq + __shfl_xor(sq, 16); sq = sq + __shfl_xor(sq, 32);
      if (lg == 0) {
        const int srow = g * 4 + mi;
        zmaxh[(size_t)srow * 512 + col] = f2bf(mx);
        zminh[(size_t)srow * 512 + col] = f2bf(mn);
      }
      colsum += sm; colssq += sq;
    }
    if (lg == 0) {
      float2 o; o.x = colsum; o.y = colssq;
      *(float2*)(&part2[(size_t)(g * 512 + col) * 2]) = o;
    }
  }
}

// ---------------- K7: finalize BN2 ----------------
__global__ __launch_bounds__(256) void k_fin2(const float* __restrict__ tmp2, const float* __restrict__ g2,
                                              const float* __restrict__ bt2,
                                              float* __restrict__ A2, float* __restrict__ B2) {
  const int ch = blockIdx.x * 256 + threadIdx.x;
  float s = 0, q = 0;
  #pragma unroll
  for (int r = 0; r < 16; ++r) { s += tmp2[r * 1024 + 2 * ch]; q += tmp2[r * 1024 + 2 * ch + 1]; }
  const float inv = 1.0f / 262144.0f;
  const float m = s * inv;
  const float var = q * inv - m * m;
  const float A = rsqrtf(var + 1e-5f) * g2[ch];
  A2[ch] = A;
  B2[ch] = bt2[ch] - m * A;
}

// ---------------- K8: final BN2+ReLU ----------------
__global__ __launch_bounds__(256) void k_out(const unsigned short* __restrict__ zmaxh,
                                             const unsigned short* __restrict__ zminh,
                                             const float* __restrict__ A2, const float* __restrict__ B2,
                                             float* __restrict__ out) {
  int v = blockIdx.x * 256 + threadIdx.x;
  for (; v < 2097152; v += gridDim.x * 256) {
    const int f = v * 4;
    const int col = f & 511;
    const float4 a = *(const float4*)(&A2[col]);
    const float4 bb = *(const float4*)(&B2[col]);
    s16x4 mxh = *(const s16x4*)(&zmaxh[f]);
    s16x4 mnh = *(const s16x4*)(&zminh[f]);
    float4 o;
    o.x = fmaxf(0.f, a.x * (a.x > 0.f ? bf2f((unsigned short)mxh[0]) : bf2f((unsigned short)mnh[0])) + bb.x);
    o.y = fmaxf(0.f, a.y * (a.y > 0.f ? bf2f((unsigned short)mxh[1]) : bf2f((unsigned short)mnh[1])) + bb.y);
    o.z = fmaxf(0.f, a.z * (a.z > 0.f ? bf2f((unsigned short)mxh[2]) : bf2f((unsigned short)mnh[2])) + bb.z);
    o.w = fmaxf(0.f, a.w * (a.w > 0.f ? bf2f((unsigned short)mxh[3]) : bf2f((unsigned short)mnh[3])) + bb.w);
    *(float4*)(&out[32768 + f]) = o;
  }
}

__global__ void k_sent_ws(float* out) { if (threadIdx.x == 0) out[0] = 54321.0f; }

extern "C" void kernel_launch(void* const* d_in, const int* in_sizes, int n_in,
                              void* d_out, int out_size, void* d_ws, size_t ws_size,
                              hipStream_t stream) {
  const float* xy   = (const float*)d_in[0];
  const float* pts  = (const float*)d_in[1];
  const float* W1   = (const float*)d_in[2];
  const float* b1   = (const float*)d_in[3];
  const float* g1   = (const float*)d_in[4];
  const float* bt1  = (const float*)d_in[5];
  const float* W2   = (const float*)d_in[6];
  const float* b2   = (const float*)d_in[7];
  const float* g2   = (const float*)d_in[8];
  const float* bt2  = (const float*)d_in[9];
  float* out = (float*)d_out;
  (void)in_sizes; (void)n_in; (void)out_size;

  char* base = (char*)d_ws;
  size_t off = 0;
  auto take = [&](size_t bytes) -> char* {
    char* r = base + off;
    off = (off + bytes + 255) & ~(size_t)255;
    return r;
  };
  int*   fpsi  = (int*)take((size_t)NB * NS * 4);
  int*   knni  = (int*)take((size_t)NPAIR * 4);
  float* xyn   = (float*)take((size_t)NPAIR * 2 * 4);
  unsigned short* W1s = (unsigned short*)take((size_t)8 * 512 * 32 * 2);
  unsigned short* W2s = (unsigned short*)take((size_t)16 * 512 * 32 * 2);
  unsigned short* P1  = (unsigned short*)take((size_t)NROWS * 512 * 2);
  float* part1 = (float*)take((size_t)1024 * 1024 * 4);
  float* tmp1  = (float*)take((size_t)4 * 1024 * 4);
  float4* coef1 = (float4*)take((size_t)512 * 16);
  float* part2 = (float*)take((size_t)4096 * 1024 * 4);
  float* tmp2  = (float*)take((size_t)16 * 1024 * 4);
  float* A2    = (float*)take((size_t)512 * 4);
  float* B2    = (float*)take((size_t)512 * 4);
  unsigned short* zmaxh = (unsigned short*)take((size_t)16384 * 512 * 2);
  unsigned short* zminh = (unsigned short*)take((size_t)16384 * 512 * 2);

  if (off > ws_size) {
    k_sent_ws<<<1, 64, 0, stream>>>(out);
    return;
  }

  k_conv<<<1024, 256, 0, stream>>>(W1, W2, W1s, W2s);
  k_fps<<<NB, 256, 0, stream>>>(xy, fpsi);
  k_knn<<<NB * NS, 256, 0, stream>>>(xy, fpsi, knni, xyn, out);
  k_p1<<<1024, 256, 0, stream>>>(pts, W1s, P1);
  k_stats1<<<1024, 256, 0, stream>>>(P1, knni, xyn, W1, b1, part1);
  k_colreduce<<<16, 256, 0, stream>>>(part1, 256, tmp1);
  k_fin1<<<2, 256, 0, stream>>>(tmp1, W1, b1, g1, bt1, coef1);
  k_main<<<4096, 256, 0, stream>>>(P1, knni, xyn, coef1, W2s, b2, part2, zmaxh, zminh);
  k_colreduce<<<64, 256, 0, stream>>>(part2, 256, tmp2);
  k_fin2<<<2, 256, 0, stream>>>(tmp2, g2, bt2, A2, B2);
  k_out<<<2048, 256, 0, stream>>>(zmaxh, zminh, A2, B2, out);
}

// Round 19
// 1776.356 us; speedup vs baseline: 1.0867x; 1.0542x over previous
//
#include <hip/hip_runtime.h>

typedef float f32x4 __attribute__((ext_vector_type(4)));
typedef short s16x8 __attribute__((ext_vector_type(8)));
typedef short s16x4 __attribute__((ext_vector_type(4)));

#define NB 16
#define NPT 4096
#define DPT 254
#define NS 1024
#define KNN 16
#define NPAIR (NB*NS*KNN)   // 262144
#define NROWS (NB*NPT)      // 65536

__device__ __forceinline__ unsigned short f2bf(float f) {
  unsigned u = __float_as_uint(f);
  u += 0x7FFFu + ((u >> 16) & 1u);   // RNE
  return (unsigned short)(u >> 16);
}
__device__ __forceinline__ float bf2f(unsigned short h) {
  return __uint_as_float(((unsigned)h) << 16);
}
// monotone float->uint order map (handles negatives)
__device__ __forceinline__ unsigned ordf(float f) {
  unsigned u = __float_as_uint(f);
  return u ^ (unsigned)(((int)u >> 31) | 0x80000000);
}
// contraction-proof f32 RN ops
__device__ __forceinline__ float vmulf(float a, float b) {
  float r; asm("v_mul_f32 %0, %1, %2" : "=v"(r) : "v"(a), "v"(b)); return r;
}
__device__ __forceinline__ float vaddf(float a, float b) {
  float r; asm("v_add_f32 %0, %1, %2" : "=v"(r) : "v"(a), "v"(b)); return r;
}
__device__ __forceinline__ float vsubf(float a, float b) {
  float r; asm("v_sub_f32 %0, %1, %2" : "=v"(r) : "v"(a), "v"(b)); return r;
}
// explicit single fma
__device__ __forceinline__ float vfmaf(float a, float b, float c) {
  float r; asm("v_fma_f32 %0, %1, %2, %3" : "=v"(r) : "v"(a), "v"(b), "v"(c)); return r;
}

// ================= K_FRONT: fused FPS (16 blk) | W2 conv (64 blk) | P1 GEMM (1024 blk) =================
// No inter-block data dependencies inside this kernel: FPS touches xy/fpsi only; W2-conv
// writes W2s (read only by later k_main); P1 converts W1 inline (never reads W1s).
__global__ __launch_bounds__(256) void k_front(const float* __restrict__ xy, int* __restrict__ fpsi,
                                               const float* __restrict__ W2, unsigned short* __restrict__ W2s,
                                               const float* __restrict__ points, const float* __restrict__ W1,
                                               unsigned short* __restrict__ P1) {
  __shared__ __align__(16) char smem[46080];
  const int gid = blockIdx.x;
  const int t = threadIdx.x;

  if (gid < 16) {
    // ---------------- FPS path (byte-identical arithmetic to verified version) ----------------
    const int b = gid;
    float* sx = (float*)smem;                         // 16KB
    float* sy = sx + NPT;                             // 16KB
    unsigned long long* wkey = (unsigned long long*)(sy + NPT);  // 2*4 u64 (offset 32768, aligned)
    for (int i = t; i < NPT; i += 256) {
      float2 v = ((const float2*)xy)[b * NPT + i];
      sx[i] = v.x; sy[i] = v.y;
    }
    __syncthreads();
    float px[16], py[16], dist[16];
    #pragma unroll
    for (int j = 0; j < 16; ++j) {
      int i = t + 256 * j;
      px[j] = sx[i]; py[j] = sy[i]; dist[j] = 1e10f;
    }
    if (t == 0) fpsi[b * NS] = 0;
    float cx = sx[0], cy = sy[0];
    for (int step = 1; step < NS; ++step) {
      float bd = -1.0f; int bi = 0;
      #pragma unroll
      for (int j = 0; j < 16; ++j) {
        float dx = vsubf(px[j], cx), dy = vsubf(py[j], cy);
        float d = vaddf(vmulf(dx, dx), vmulf(dy, dy));
        float nd = fminf(dist[j], d);
        dist[j] = nd;
        if (nd > bd) { bd = nd; bi = t + 256 * j; }
      }
      unsigned long long key = ((unsigned long long)ordf(bd) << 32) | (unsigned)(0xFFFFFFFFu ^ (unsigned)bi);
      #pragma unroll
      for (int off = 32; off; off >>= 1) {
        unsigned long long o = __shfl_xor(key, off);
        key = (o > key) ? o : key;
      }
      if ((t & 63) == 0) wkey[(step & 1) * 4 + (t >> 6)] = key;
      __syncthreads();
      unsigned long long k0 = wkey[(step & 1) * 4 + 0], k1 = wkey[(step & 1) * 4 + 1];
      unsigned long long k2 = wkey[(step & 1) * 4 + 2], k3 = wkey[(step & 1) * 4 + 3];
      unsigned long long m = k0 > k1 ? k0 : k1;
      unsigned long long n = k2 > k3 ? k2 : k3;
      m = m > n ? m : n;
      const int fi = (int)(0xFFFFFFFFu ^ (unsigned)m);
      if (t == 0) fpsi[b * NS + step] = fi;
      cx = sx[fi]; cy = sy[fi];
    }
  } else if (gid < 80) {
    // ---------------- W2 -> bf16 staged layout [chunk][col][kk] ----------------
    const int i0 = (gid - 16) * 4096 + t;
    #pragma unroll
    for (int k = 0; k < 16; ++k) {
      const int i = i0 + k * 256;
      const int kk = i & 31, col = (i >> 5) & 511, c = i >> 14;
      W2s[i] = f2bf(W2[(c * 32 + kk) * 512 + col]);
    }
  } else {
    // ---------------- P1 = pad2(points) @ W1 (bf16 MFMA), inline W1 conversion ----------------
    const int rt = gid - 80;
    const int l = t & 63, w = t >> 6;
    unsigned short* sA = (unsigned short*)smem;        // 64*40*2 = 5120
    unsigned short* sB = sA + 64 * 40;                 // 512*40*2 = 40960
    f32x4 acc[4][8];
    #pragma unroll
    for (int mi = 0; mi < 4; ++mi)
      #pragma unroll
      for (int ni = 0; ni < 8; ++ni) acc[mi][ni] = (f32x4){0.f, 0.f, 0.f, 0.f};
    for (int c = 0; c < 8; ++c) {
      __syncthreads();
      { // stage A: rows of padded points, f32 -> bf16
        const int r = t >> 2, kk = (t & 3) * 8;
        const int m = rt * 64 + r;
        s16x8 av;
        #pragma unroll
        for (int j = 0; j < 8; ++j) {
          const int cc = c * 32 + kk + j;
          const float f = (cc >= 2) ? points[(size_t)m * DPT + (cc - 2)] : 0.0f;
          av[j] = (short)f2bf(f);
        }
        *(s16x8*)(&sA[r * 40 + kk]) = av;
      }
      { // stage B: W1 chunk converted inline (same values as staged layout)
        #pragma unroll
        for (int qd = 0; qd < 8; ++qd) {
          const int e = t * 64 + qd * 8;
          const int col = e >> 5, kk = e & 31;
          s16x8 bv8;
          #pragma unroll
          for (int j = 0; j < 8; ++j)
            bv8[j] = (short)f2bf(W1[(c * 32 + kk + j) * 512 + col]);
          *(s16x8*)(&sB[col * 40 + kk]) = bv8;
        }
      }
      __syncthreads();
      s16x8 a[4];
      #pragma unroll
      for (int mi = 0; mi < 4; ++mi)
        a[mi] = *(const s16x8*)(&sA[(mi * 16 + (l & 15)) * 40 + (l >> 4) * 8]);
      #pragma unroll
      for (int ni = 0; ni < 8; ++ni) {
        const s16x8 bv = *(const s16x8*)(&sB[(w * 128 + ni * 16 + (l & 15)) * 40 + (l >> 4) * 8]);
        #pragma unroll
        for (int mi = 0; mi < 4; ++mi)
          acc[mi][ni] = __builtin_amdgcn_mfma_f32_16x16x32_bf16(a[mi], bv, acc[mi][ni], 0, 0, 0);
      }
    }
    #pragma unroll
    for (int mi = 0; mi < 4; ++mi)
      #pragma unroll
      for (int ni = 0; ni < 8; ++ni)
        #pragma unroll
        for (int r = 0; r < 4; ++r) {
          const int row = rt * 64 + mi * 16 + (l >> 4) * 4 + r;
          const int col = w * 128 + ni * 16 + (l & 15);
          P1[(size_t)row * 512 + col] = f2bf(acc[mi][ni][r]);
        }
  }
}

// ---------------- K2: 16-NN; dot = fma(qy,by, RN(qx*bx)) — verified golden semantics ----------------
__global__ __launch_bounds__(256) void k_knn(const float* __restrict__ xy, const int* __restrict__ fpsi,
                                             int* __restrict__ knni, float* __restrict__ xyn,
                                             float* __restrict__ out_newxy) {
  const int q = blockIdx.x;           // b*NS + s
  const int b = q >> 10;
  const int t = threadIdx.x;
  __shared__ unsigned long long wmin[2][4];
  const int qi = fpsi[q];
  float2 qv = ((const float2*)xy)[b * NPT + qi];
  const float qx = qv.x, qy = qv.y;
  if (t == 0) { out_newxy[q * 2 + 0] = qx; out_newxy[q * 2 + 1] = qy; }
  const float sa = vaddf(vmulf(qx, qx), vmulf(qy, qy));
  float px[16], py[16];
  unsigned long long ku[16], cmin = ~0ull;
  #pragma unroll
  for (int j = 0; j < 16; ++j) {
    const int i = t + 256 * j;
    float2 v = ((const float2*)xy)[b * NPT + i];
    px[j] = v.x; py[j] = v.y;
    const float sb = vaddf(vmulf(v.x, v.x), vmulf(v.y, v.y));
    const float dot = vfmaf(qy, v.y, vmulf(qx, v.x));   // acc=RN(qx*bx); dot=fma(qy,by,acc)
    const float d = vsubf(vaddf(sa, sb), vmulf(2.0f, dot));
    ku[j] = ((unsigned long long)ordf(d) << 32) | (unsigned)i;   // tie: lowest index first
    cmin = ku[j] < cmin ? ku[j] : cmin;
  }
  for (int r = 0; r < KNN; ++r) {
    unsigned long long key = cmin;
    #pragma unroll
    for (int off = 32; off; off >>= 1) {
      unsigned long long o = __shfl_xor(key, off);
      key = o < key ? o : key;
    }
    if ((t & 63) == 0) wmin[r & 1][t >> 6] = key;
    __syncthreads();
    unsigned long long m0 = wmin[r & 1][0], m1 = wmin[r & 1][1];
    unsigned long long m2 = wmin[r & 1][2], m3 = wmin[r & 1][3];
    unsigned long long m = m0 < m1 ? m0 : m1;
    unsigned long long n = m2 < m3 ? m2 : m3;
    m = m < n ? m : n;
    if (m == cmin) {  // unique owner (idx embedded in key)
      const unsigned widx = (unsigned)m;
      const int jj0 = (int)(widx >> 8);
      cmin = ~0ull;
      #pragma unroll
      for (int j = 0; j < 16; ++j) {
        if (j == jj0) {
          ku[j] = ~0ull;
          knni[q * KNN + r] = (int)widx;
          xyn[(q * KNN + r) * 2 + 0] = vsubf(px[j], qx);
          xyn[(q * KNN + r) * 2 + 1] = vsubf(py[j], qy);
        }
        cmin = ku[j] < cmin ? ku[j] : cmin;
      }
    }
  }
}

// ---------------- K4: layer-1 pre-activation stats ----------------
__global__ __launch_bounds__(256) void k_stats1(const unsigned short* __restrict__ P1,
                                                const int* __restrict__ knni, const float* __restrict__ xyn,
                                                const float* __restrict__ W1, const float* __restrict__ b1,
                                                float* __restrict__ part1) {
  const int blk = blockIdx.x;
  const int t = threadIdx.x;
  __shared__ int sgidx[256];
  __shared__ float sxn[256][2];
  const int p = blk * 256 + t;
  const int b = p >> 14;
  sgidx[t] = b * NPT + knni[p];
  sxn[t][0] = xyn[p * 2 + 0]; sxn[t][1] = xyn[p * 2 + 1];
  __syncthreads();
  const int ch0 = 2 * t;
  const float w00 = W1[ch0], w01 = W1[ch0 + 1];
  const float w10 = W1[512 + ch0], w11 = W1[512 + ch0 + 1];
  const float bb0 = b1[ch0], bb1 = b1[ch0 + 1];
  float s0 = 0, s1 = 0, q0 = 0, q1 = 0;
  for (int i = 0; i < 256; ++i) {
    const int row = sgidx[i];
    const float xn = sxn[i][0], yn = sxn[i][1];
    unsigned v = *(const unsigned*)(&P1[(size_t)row * 512 + ch0]);
    float z0 = bf2f((unsigned short)v) + xn * w00 + yn * w10 + bb0;
    float z1 = bf2f((unsigned short)(v >> 16)) + xn * w01 + yn * w11 + bb1;
    s0 += z0; q0 += z0 * z0; s1 += z1; q1 += z1 * z1;
  }
  float4 o; o.x = s0; o.y = q0; o.z = s1; o.w = q1;
  *(float4*)(&part1[(size_t)(blk * 512 + ch0) * 2]) = o;
}

// ---------------- column reduce ----------------
__global__ __launch_bounds__(256) void k_colreduce(const float* __restrict__ part, int rows_per_blk,
                                                   float* __restrict__ out) {
  const int cs = blockIdx.x & 3, rs = blockIdx.x >> 2;
  const int col = cs * 256 + threadIdx.x;
  float s = 0;
  const int r0 = rs * rows_per_blk;
  for (int r = 0; r < rows_per_blk; ++r) s += part[(size_t)(r0 + r) * 1024 + col];
  out[rs * 1024 + col] = s;
}

// ---------------- K5: finalize BN1 ----------------
__global__ __launch_bounds__(256) void k_fin1(const float* __restrict__ tmp1, const float* __restrict__ W1,
                                              const float* __restrict__ b1, const float* __restrict__ g1,
                                              const float* __restrict__ bt1, float4* __restrict__ coef1) {
  const int ch = blockIdx.x * 256 + threadIdx.x;
  float s = 0, q = 0;
  #pragma unroll
  for (int r = 0; r < 4; ++r) { s += tmp1[r * 1024 + 2 * ch]; q += tmp1[r * 1024 + 2 * ch + 1]; }
  const float inv = 1.0f / 262144.0f;
  const float m = s * inv;
  const float var = q * inv - m * m;
  const float A = rsqrtf(var + 1e-5f) * g1[ch];
  const float Bv = bt1[ch] - m * A;
  float4 cf;
  cf.x = A; cf.y = W1[ch] * A; cf.z = W1[512 + ch] * A; cf.w = b1[ch] * A + Bv;
  coef1[ch] = cf;
}

// ---------------- K6: fused h1 -> GEMM2 -> z2 stats + max/min over K ----------------
__global__ __launch_bounds__(256) void k_main(const unsigned short* __restrict__ P1,
                                              const int* __restrict__ knni, const float* __restrict__ xyn,
                                              const float4* __restrict__ coef1,
                                              const unsigned short* __restrict__ W2s,
                                              const float* __restrict__ b2,
                                              float* __restrict__ part2,
                                              unsigned short* __restrict__ zmaxh, unsigned short* __restrict__ zminh) {
  const int g = blockIdx.x;
  const int t = threadIdx.x, l = t & 63, w = t >> 6;
  __shared__ unsigned short sH[64 * 40];
  __shared__ unsigned short sW[512 * 40];
  __shared__ int sgidx[64];
  __shared__ float sxn[64][2];
  if (t < 64) {
    const int p = g * 64 + t;
    const int b = p >> 14;
    sgidx[t] = b * NPT + knni[p];
    sxn[t][0] = xyn[p * 2 + 0]; sxn[t][1] = xyn[p * 2 + 1];
  }
  f32x4 acc[4][8];
  #pragma unroll
  for (int mi = 0; mi < 4; ++mi)
    #pragma unroll
    for (int ni = 0; ni < 8; ++ni) acc[mi][ni] = (f32x4){0.f, 0.f, 0.f, 0.f};
  const int skk = t & 31;
  const int sr0 = (t >> 5) * 8;
  for (int c = 0; c < 16; ++c) {
    __syncthreads();
    {
      const int ch = c * 32 + skk;
      const float4 cf = coef1[ch];
      #pragma unroll
      for (int qq = 0; qq < 8; ++qq) {
        const int r = sr0 + qq;
        const int row = sgidx[r];
        const float pv = bf2f(P1[(size_t)row * 512 + ch]);
        const float h = fmaxf(0.0f, pv * cf.x + sxn[r][0] * cf.y + sxn[r][1] * cf.z + cf.w);
        sH[r * 40 + skk] = f2bf(h);
      }
    }
    {
      const unsigned short* src = &W2s[c * 16384];
      #pragma unroll
      for (int qd = 0; qd < 8; ++qd) {
        const int e = t * 64 + qd * 8;
        const int col = e >> 5, kk = e & 31;
        *(s16x8*)(&sW[col * 40 + kk]) = *(const s16x8*)(&src[e]);
      }
    }
    __syncthreads();
    s16x8 a[4];
    #pragma unroll
    for (int mi = 0; mi < 4; ++mi)
      a[mi] = *(const s16x8*)(&sH[(mi * 16 + (l & 15)) * 40 + (l >> 4) * 8]);
    #pragma unroll
    for (int ni = 0; ni < 8; ++ni) {
      const s16x8 bv = *(const s16x8*)(&sW[(w * 128 + ni * 16 + (l & 15)) * 40 + (l >> 4) * 8]);
      #pragma unroll
      for (int mi = 0; mi < 4; ++mi)
        acc[mi][ni] = __builtin_amdgcn_mfma_f32_16x16x32_bf16(a[mi], bv, acc[mi][ni], 0, 0, 0);
    }
  }
  const int cl = l & 15, lg = l >> 4;
  #pragma unroll
  for (int ni = 0; ni < 8; ++ni) {
    const int col = w * 128 + ni * 16 + cl;
    const float b2v = b2[col];
    float colsum = 0, colssq = 0;
    #pragma unroll
    for (int mi = 0; mi < 4; ++mi) {
      f32x4 v = acc[mi][ni];
      #pragma unroll
      for (int r = 0; r < 4; ++r) v[r] += b2v;
      float mx = fmaxf(fmaxf(v[0], v[1]), fmaxf(v[2], v[3]));
      float mn = fminf(fminf(v[0], v[1]), fminf(v[2], v[3]));
      float sm = v[0] + v[1] + v[2] + v[3];
      float sq = v[0] * v[0] + v[1] * v[1] + v[2] * v[2] + v[3] * v[3];
      mx = fmaxf(mx, __shfl_xor(mx, 16)); mx = fmaxf(mx, __shfl_xor(mx, 32));
      mn = fminf(mn, __shfl_xor(mn, 16)); mn = fminf(mn, __shfl_xor(mn, 32));
      sm = sm + __shfl_xor(sm, 16); sm = sm + __shfl_xor(sm, 32);
      sq = sq + __shfl_xor(sq, 16); sq = sq + __shfl_xor(sq, 32);
      if (lg == 0) {
        const int srow = g * 4 + mi;
        zmaxh[(size_t)srow * 512 + col] = f2bf(mx);
        zminh[(size_t)srow * 512 + col] = f2bf(mn);
      }
      colsum += sm; colssq += sq;
    }
    if (lg == 0) {
      float2 o; o.x = colsum; o.y = colssq;
      *(float2*)(&part2[(size_t)(g * 512 + col) * 2]) = o;
    }
  }
}

// ---------------- K7: finalize BN2 ----------------
__global__ __launch_bounds__(256) void k_fin2(const float* __restrict__ tmp2, const float* __restrict__ g2,
                                              const float* __restrict__ bt2,
                                              float* __restrict__ A2, float* __restrict__ B2) {
  const int ch = blockIdx.x * 256 + threadIdx.x;
  float s = 0, q = 0;
  #pragma unroll
  for (int r = 0; r < 16; ++r) { s += tmp2[r * 1024 + 2 * ch]; q += tmp2[r * 1024 + 2 * ch + 1]; }
  const float inv = 1.0f / 262144.0f;
  const float m = s * inv;
  const float var = q * inv - m * m;
  const float A = rsqrtf(var + 1e-5f) * g2[ch];
  A2[ch] = A;
  B2[ch] = bt2[ch] - m * A;
}

// ---------------- K8: final BN2+ReLU ----------------
__global__ __launch_bounds__(256) void k_out(const unsigned short* __restrict__ zmaxh,
                                             const unsigned short* __restrict__ zminh,
                                             const float* __restrict__ A2, const float* __restrict__ B2,
                                             float* __restrict__ out) {
  int v = blockIdx.x * 256 + threadIdx.x;
  for (; v < 2097152; v += gridDim.x * 256) {
    const int f = v * 4;
    const int col = f & 511;
    const float4 a = *(const float4*)(&A2[col]);
    const float4 bb = *(const float4*)(&B2[col]);
    s16x4 mxh = *(const s16x4*)(&zmaxh[f]);
    s16x4 mnh = *(const s16x4*)(&zminh[f]);
    float4 o;
    o.x = fmaxf(0.f, a.x * (a.x > 0.f ? bf2f((unsigned short)mxh[0]) : bf2f((unsigned short)mnh[0])) + bb.x);
    o.y = fmaxf(0.f, a.y * (a.y > 0.f ? bf2f((unsigned short)mxh[1]) : bf2f((unsigned short)mnh[1])) + bb.y);
    o.z = fmaxf(0.f, a.z * (a.z > 0.f ? bf2f((unsigned short)mxh[2]) : bf2f((unsigned short)mnh[2])) + bb.z);
    o.w = fmaxf(0.f, a.w * (a.w > 0.f ? bf2f((unsigned short)mxh[3]) : bf2f((unsigned short)mnh[3])) + bb.w);
    *(float4*)(&out[32768 + f]) = o;
  }
}

__global__ void k_sent_ws(float* out) { if (threadIdx.x == 0) out[0] = 54321.0f; }

extern "C" void kernel_launch(void* const* d_in, const int* in_sizes, int n_in,
                              void* d_out, int out_size, void* d_ws, size_t ws_size,
                              hipStream_t stream) {
  const float* xy   = (const float*)d_in[0];
  const float* pts  = (const float*)d_in[1];
  const float* W1   = (const float*)d_in[2];
  const float* b1   = (const float*)d_in[3];
  const float* g1   = (const float*)d_in[4];
  const float* bt1  = (const float*)d_in[5];
  const float* W2   = (const float*)d_in[6];
  const float* b2   = (const float*)d_in[7];
  const float* g2   = (const float*)d_in[8];
  const float* bt2  = (const float*)d_in[9];
  float* out = (float*)d_out;
  (void)in_sizes; (void)n_in; (void)out_size;

  char* base = (char*)d_ws;
  size_t off = 0;
  auto take = [&](size_t bytes) -> char* {
    char* r = base + off;
    off = (off + bytes + 255) & ~(size_t)255;
    return r;
  };
  int*   fpsi  = (int*)take((size_t)NB * NS * 4);
  int*   knni  = (int*)take((size_t)NPAIR * 4);
  float* xyn   = (float*)take((size_t)NPAIR * 2 * 4);
  unsigned short* W2s = (unsigned short*)take((size_t)16 * 512 * 32 * 2);
  unsigned short* P1  = (unsigned short*)take((size_t)NROWS * 512 * 2);
  float* part1 = (float*)take((size_t)1024 * 1024 * 4);
  float* tmp1  = (float*)take((size_t)4 * 1024 * 4);
  float4* coef1 = (float4*)take((size_t)512 * 16);
  float* part2 = (float*)take((size_t)4096 * 1024 * 4);
  float* tmp2  = (float*)take((size_t)16 * 1024 * 4);
  float* A2    = (float*)take((size_t)512 * 4);
  float* B2    = (float*)take((size_t)512 * 4);
  unsigned short* zmaxh = (unsigned short*)take((size_t)16384 * 512 * 2);
  unsigned short* zminh = (unsigned short*)take((size_t)16384 * 512 * 2);

  if (off > ws_size) {
    k_sent_ws<<<1, 64, 0, stream>>>(out);
    return;
  }

  k_front<<<1104, 256, 0, stream>>>(xy, fpsi, W2, W2s, pts, W1, P1);
  k_knn<<<NB * NS, 256, 0, stream>>>(xy, fpsi, knni, xyn, out);
  k_stats1<<<1024, 256, 0, stream>>>(P1, knni, xyn, W1, b1, part1);
  k_colreduce<<<16, 256, 0, stream>>>(part1, 256, tmp1);
  k_fin1<<<2, 256, 0, stream>>>(tmp1, W1, b1, g1, bt1, coef1);
  k_main<<<4096, 256, 0, stream>>>(P1, knni, xyn, coef1, W2s, b2, part2, zmaxh, zminh);
  k_colreduce<<<64, 256, 0, stream>>>(part2, 256, tmp2);
  k_fin2<<<2, 256, 0, stream>>>(tmp2, g2, bt2, A2, B2);
  k_out<<<2048, 256, 0, stream>>>(zmaxh, zminh, A2, B2, out);
}